// Round 2
// baseline (206.454 us; speedup 1.0000x reference)
//
#include <hip/hip_runtime.h>

#define C_DIM 128
#define EPS 1e-5f
#define NSCAT 1250  // scatter blocks; NSCAT*256 = 320000 = E/2

typedef __attribute__((ext_vector_type(8))) short short8;
typedef __attribute__((ext_vector_type(4))) float f32x4;

__device__ __forceinline__ unsigned bf16rn(float f) {
    unsigned u = __float_as_uint(f);
    return (u + 0x7fffu + ((u >> 16) & 1u)) >> 16;
}
__device__ __forceinline__ unsigned pack_bf16(float lo, float hi) {
    return bf16rn(lo) | (bf16rn(hi) << 16);
}
__device__ __forceinline__ float blo(unsigned u) { return __uint_as_float(u << 16); }
__device__ __forceinline__ float bhi(unsigned u) { return __uint_as_float(u & 0xffff0000u); }

// ---------------- prep0: zero counters + build W_conv^T hi/lo bf16 + W_fc^T bf16 ----
__global__ void prep0(const float* __restrict__ W, const float* __restrict__ Wfc,
                      unsigned short* __restrict__ WhT, unsigned short* __restrict__ WlT,
                      unsigned short* __restrict__ WT,
                      int* __restrict__ cntA, int* __restrict__ cntB, int n) {
    int gid = blockIdx.x * blockDim.x + threadIdx.x;
    int stride = gridDim.x * blockDim.x;
    for (int t = gid; t < 128 * 128; t += stride) {
        int c = t >> 7, k = t & 127;
        float v = W[k * 128 + c];
        unsigned hi = bf16rn(v);
        float fh = __uint_as_float(hi << 16);
        WhT[c * 128 + k] = (unsigned short)hi;
        WlT[c * 128 + k] = (unsigned short)bf16rn(v - fh);
    }
    for (int t = gid; t < 48 * 128; t += stride) {
        int nc = t >> 7, k = t & 127;
        WT[nc * 128 + k] = (unsigned short)((nc < 40) ? bf16rn(Wfc[k * 40 + nc]) : 0u);
    }
    for (int t = gid; t < n; t += stride) {
        cntA[t] = 0;
        cntB[t] = 0;
    }
}

// ---------------- FAT: edge scatter (two-ended buckets) | gemm1 split-bf16 MFMA ----
// gemm1 = xh*Wh + xl*Wh + xh*Wl (bf16 hi/lo split ~ fp32 accuracy), ZERO LDS ->
// 4 blocks/CU for 2x the atomic memory-level parallelism in scatter blocks.
__global__ __launch_bounds__(256, 4) void fat(const float* __restrict__ x,
                                              const unsigned short* __restrict__ WhT,
                                              const unsigned short* __restrict__ WlT,
                                              unsigned short* __restrict__ hbs,
                                              const int* __restrict__ esrc,
                                              const int* __restrict__ edst,
                                              int* __restrict__ cntA,
                                              int* __restrict__ cntB,
                                              unsigned short* __restrict__ bsrcu,
                                              int n, int e) {
    int b = blockIdx.x;
    int t = threadIdx.x;

    if (b < NSCAT) {
        // first edge half -> cntA / front of bucket; second half -> cntB / back.
        int half = NSCAT * 256;
        int i = b * 256 + t;
        int j = i + half;
        if (i < e) {
            int d0 = edst[i], s0 = esrc[i];
            int p0 = atomicAdd(&cntA[d0], 1);
            if (p0 < 64) bsrcu[(long)d0 * 64 + p0] = (unsigned short)s0;
        }
        if (j < e) {
            int d1 = edst[j], s1 = esrc[j];
            int p1 = atomicAdd(&cntB[d1], 1);
            if (p1 < 64) bsrcu[(long)d1 * 64 + 63 - p1] = (unsigned short)s1;
        }
    } else {
        // ---- gemm1: h = x @ W_conv via 16x16x32 bf16 MFMA, hi/lo split, no LDS ----
        int r0 = (b - NSCAT) * 128;
        int wid = t >> 6, lane = t & 63;
        int mrow = lane & 15, quad = lane >> 4;
        int rb = r0 + wid * 32;  // wave owns 32 rows x 128 cols

        f32x4 acc[2][8];
#pragma unroll
        for (int m = 0; m < 2; m++)
#pragma unroll
            for (int nn = 0; nn < 8; nn++) acc[m][nn] = (f32x4){0.f, 0.f, 0.f, 0.f};

#pragma unroll
        for (int ks = 0; ks < 4; ks++) {
            short8 Ah[2], Al[2];
#pragma unroll
            for (int m = 0; m < 2; m++) {
                int r = rb + m * 16 + mrow;
                if (r >= n) r = n - 1;  // clamp loads; stores guarded
                const float* xp = &x[(long)r * C_DIM + ks * 32 + quad * 8];
                float4 va = *(const float4*)xp;
                float4 vb = *(const float4*)(xp + 4);
                float xv[8] = {va.x, va.y, va.z, va.w, vb.x, vb.y, vb.z, vb.w};
#pragma unroll
                for (int e8 = 0; e8 < 8; e8++) {
                    unsigned hi = bf16rn(xv[e8]);
                    Ah[m][e8] = (short)hi;
                    Al[m][e8] = (short)bf16rn(xv[e8] - __uint_as_float(hi << 16));
                }
            }
#pragma unroll
            for (int nn = 0; nn < 8; nn++) {
                int wof = (nn * 16 + mrow) * 128 + ks * 32 + quad * 8;
                short8 Bh = *(const short8*)&WhT[wof];
                short8 Bl = *(const short8*)&WlT[wof];
#pragma unroll
                for (int m = 0; m < 2; m++) {
                    acc[m][nn] = __builtin_amdgcn_mfma_f32_16x16x32_bf16(Ah[m], Bh, acc[m][nn], 0, 0, 0);
                    acc[m][nn] = __builtin_amdgcn_mfma_f32_16x16x32_bf16(Al[m], Bh, acc[m][nn], 0, 0, 0);
                    acc[m][nn] = __builtin_amdgcn_mfma_f32_16x16x32_bf16(Ah[m], Bl, acc[m][nn], 0, 0, 0);
                }
            }
        }
        // C/D layout (same as verified gemm2): row = quad*4 + reg, col = nn*16 + mrow
#pragma unroll
        for (int m = 0; m < 2; m++)
#pragma unroll
            for (int nn = 0; nn < 8; nn++) {
                int c = nn * 16 + mrow;
#pragma unroll
                for (int reg = 0; reg < 4; reg++) {
                    int r = rb + m * 16 + quad * 4 + reg;
                    if (r < n) hbs[(long)r * 128 + c] = (unsigned short)bf16rn(acc[m][nn][reg]);
                }
            }
    }
}

// ---------------- fused aggregate + bias + relu*x + LN + residual --------------
// One wave per node; slot table (src id + weight) loaded/computed once across the
// 64 lanes. CRITICAL: the gather loop below is WAVE-UNIFORM (trip count depends
// only on tot, identical for all lanes). On CDNA, __shfl = ds_bpermute, and a
// pull from an INACTIVE source lane returns 0 — a divergent loop here silently
// drops neighbors (round-1 bug). Out-of-range slots are handled by predication
// AFTER the shuffle (w=0, s=self so the dead gather is an L1 hit).
__global__ __launch_bounds__(256) void aggregate(const unsigned* __restrict__ hb,
                                                 const float* __restrict__ x,
                                                 const int* __restrict__ cntA,
                                                 const int* __restrict__ cntB,
                                                 const unsigned short* __restrict__ bsrcu,
                                                 const float* __restrict__ bconv,
                                                 const float* __restrict__ gamma,
                                                 const float* __restrict__ beta,
                                                 unsigned* __restrict__ zb, int n) {
    int wid = (blockIdx.x * blockDim.x + threadIdx.x) >> 6;
    if (wid >= n) return;  // wave-uniform
    int lane = threadIdx.x & 63;
    int sub = lane & 15, grp = lane >> 4;
    int i = wid;

    int dA = cntA[i], dB = cntB[i];
    float di = rsqrtf((float)(dA + dB) + 1.0f);  // full degree for norm
    if (dA > 64) dA = 64;
    if (dB > 64 - dA) dB = 64 - dA;
    int tot = dA + dB;
    int shift = 64 - tot;  // maps compact index t in [dA,tot) to back region

    // slot table: lane <-> bucket slot (front region [0,dA), back [64-dB,64))
    int sraw = (int)bsrcu[(long)i * 64 + lane];
    bool valid = (lane < dA) | (lane >= 64 - dB);
    int s_all = valid ? sraw : 0;
    float w_all = valid ? rsqrtf((float)(cntA[s_all] + cntB[s_all]) + 1.0f) * di : 0.f;

    uint4 us = *(const uint4*)(hb + (long)i * 64 + sub * 4);
    float wself = (grp == 0) ? di * di : 0.f;
    float acc[8];
    acc[0] = wself * blo(us.x); acc[1] = wself * bhi(us.x);
    acc[2] = wself * blo(us.y); acc[3] = wself * bhi(us.y);
    acc[4] = wself * blo(us.z); acc[5] = wself * bhi(us.z);
    acc[6] = wself * blo(us.w); acc[7] = wself * bhi(us.w);

    int nIt = (tot + 7) >> 3;  // UNIFORM trip count; 8 slots (2 per grp) per iter
    for (int it = 0; it < nIt; ++it) {
        int t0 = grp + it * 8;
        int t1 = t0 + 4;
        int sl0 = ((t0 < dA) ? t0 : t0 + shift) & 63;
        int sl1 = ((t1 < dA) ? t1 : t1 + shift) & 63;
        int s0 = __shfl(s_all, sl0);      // full-exec bpermute
        float w0 = __shfl(w_all, sl0);
        int s1 = __shfl(s_all, sl1);
        float w1 = __shfl(w_all, sl1);
        if (t0 >= tot) { w0 = 0.f; s0 = i; }  // predicate AFTER shuffle
        if (t1 >= tot) { w1 = 0.f; s1 = i; }
        uint4 u0 = *(const uint4*)(hb + (long)s0 * 64 + sub * 4);
        uint4 u1 = *(const uint4*)(hb + (long)s1 * 64 + sub * 4);
        acc[0] += w0 * blo(u0.x); acc[1] += w0 * bhi(u0.x);
        acc[2] += w0 * blo(u0.y); acc[3] += w0 * bhi(u0.y);
        acc[4] += w0 * blo(u0.z); acc[5] += w0 * bhi(u0.z);
        acc[6] += w0 * blo(u0.w); acc[7] += w0 * bhi(u0.w);
        acc[0] += w1 * blo(u1.x); acc[1] += w1 * bhi(u1.x);
        acc[2] += w1 * blo(u1.y); acc[3] += w1 * bhi(u1.y);
        acc[4] += w1 * blo(u1.z); acc[5] += w1 * bhi(u1.z);
        acc[6] += w1 * blo(u1.w); acc[7] += w1 * bhi(u1.w);
    }

#pragma unroll
    for (int j = 0; j < 8; j++) {
        acc[j] += __shfl_xor(acc[j], 16);
        acc[j] += __shfl_xor(acc[j], 32);
    }

    float4 bca = *(const float4*)&bconv[sub * 8];
    float4 bcb = *(const float4*)&bconv[sub * 8 + 4];
    float4 xa  = *(const float4*)&x[(long)i * C_DIM + sub * 8];
    float4 xb  = *(const float4*)&x[(long)i * C_DIM + sub * 8 + 4];
    float a[8], xv[8];
    xv[0] = xa.x; xv[1] = xa.y; xv[2] = xa.z; xv[3] = xa.w;
    xv[4] = xb.x; xv[5] = xb.y; xv[6] = xb.z; xv[7] = xb.w;
    float bc[8] = {bca.x, bca.y, bca.z, bca.w, bcb.x, bcb.y, bcb.z, bcb.w};
#pragma unroll
    for (int j = 0; j < 8; j++) a[j] = fmaxf(acc[j] + bc[j], 0.f) * xv[j];

    float s = a[0] + a[1] + a[2] + a[3] + a[4] + a[5] + a[6] + a[7];
#pragma unroll
    for (int off = 1; off < 16; off <<= 1) s += __shfl_xor(s, off);
    float mu = s * (1.0f / 128.0f);
    float d[8], v = 0.f;
#pragma unroll
    for (int j = 0; j < 8; j++) { d[j] = a[j] - mu; v += d[j] * d[j]; }
#pragma unroll
    for (int off = 1; off < 16; off <<= 1) v += __shfl_xor(v, off);
    float inv = rsqrtf(v * (1.0f / 128.0f) + EPS);

    if (grp == 0) {
        float4 ga = *(const float4*)&gamma[sub * 8];
        float4 gb = *(const float4*)&gamma[sub * 8 + 4];
        float4 ba = *(const float4*)&beta[sub * 8];
        float4 bb = *(const float4*)&beta[sub * 8 + 4];
        float g[8] = {ga.x, ga.y, ga.z, ga.w, gb.x, gb.y, gb.z, gb.w};
        float be[8] = {ba.x, ba.y, ba.z, ba.w, bb.x, bb.y, bb.z, bb.w};
        float o[8];
#pragma unroll
        for (int j = 0; j < 8; j++) o[j] = d[j] * inv * g[j] + be[j] + xv[j];
        uint4 p;
        p.x = pack_bf16(o[0], o[1]);
        p.y = pack_bf16(o[2], o[3]);
        p.z = pack_bf16(o[4], o[5]);
        p.w = pack_bf16(o[6], o[7]);
        *(uint4*)(zb + (long)i * 64 + sub * 4) = p;
    }
}

// ---------------- GEMM2: out = z @ W_fc + b_fc via bf16 MFMA, no LDS ----------------
__global__ __launch_bounds__(256) void gemm2(const unsigned short* __restrict__ zb,
                                             const unsigned short* __restrict__ WT,
                                             const float* __restrict__ bfc,
                                             float* __restrict__ out, int n) {
    int t = threadIdx.x;
    int w = t >> 6, lane = t & 63;
    int r0 = (blockIdx.x * 4 + w) * 64;
    if (r0 >= n) return;
    int mrow = lane & 15;
    int quad = lane >> 4;
    f32x4 acc[4][3];
#pragma unroll
    for (int m = 0; m < 4; m++)
#pragma unroll
        for (int nt = 0; nt < 3; nt++) acc[m][nt] = (f32x4){0.f, 0.f, 0.f, 0.f};
#pragma unroll
    for (int ks = 0; ks < 4; ks++) {
        short8 A[4], B[3];
#pragma unroll
        for (int m = 0; m < 4; m++) {
            int r = r0 + m * 16 + mrow;
            if (r >= n) r = n - 1;  // clamp (stores are guarded)
            A[m] = *(const short8*)&zb[(long)r * 128 + ks * 32 + quad * 8];
        }
#pragma unroll
        for (int nt = 0; nt < 3; nt++)
            B[nt] = *(const short8*)&WT[(nt * 16 + mrow) * 128 + ks * 32 + quad * 8];
#pragma unroll
        for (int m = 0; m < 4; m++)
#pragma unroll
            for (int nt = 0; nt < 3; nt++)
                acc[m][nt] = __builtin_amdgcn_mfma_f32_16x16x32_bf16(A[m], B[nt], acc[m][nt], 0, 0, 0);
    }
#pragma unroll
    for (int nt = 0; nt < 3; nt++) {
        int c = nt * 16 + mrow;
        if (c < 40) {
            float bias = bfc[c];
#pragma unroll
            for (int m = 0; m < 4; m++) {
#pragma unroll
                for (int reg = 0; reg < 4; reg++) {
                    int r = r0 + m * 16 + quad * 4 + reg;
                    if (r < n) out[(long)r * 40 + c] = acc[m][nt][reg] + bias;
                }
            }
        }
    }
}

extern "C" void kernel_launch(void* const* d_in, const int* in_sizes, int n_in,
                              void* d_out, int out_size, void* d_ws, size_t ws_size,
                              hipStream_t stream) {
    const float* x     = (const float*)d_in[0];
    const int*   ei    = (const int*)d_in[1];
    const float* Wc    = (const float*)d_in[2];
    const float* bc    = (const float*)d_in[3];
    const float* gamma = (const float*)d_in[4];
    const float* beta  = (const float*)d_in[5];
    const float* Wfc   = (const float*)d_in[6];
    const float* bfc   = (const float*)d_in[7];
    float* out = (float*)d_out;

    int N = in_sizes[0] / C_DIM;
    int E = in_sizes[1] / 2;
    const int* esrc = ei;
    const int* edst = ei + E;

    char* p = (char*)d_ws;
    auto carve = [&](size_t bytes) {
        void* q = (void*)p;
        p += (bytes + 255) & ~(size_t)255;
        return q;
    };
    unsigned* hb        = (unsigned*)carve((size_t)N * 64 * 4);   // h bf16 pairs
    unsigned* zb        = (unsigned*)carve((size_t)N * 64 * 4);   // z bf16 pairs
    unsigned short* WT  = (unsigned short*)carve(48 * 128 * 2);   // W_fc^T bf16
    unsigned short* WhT = (unsigned short*)carve(128 * 128 * 2);  // W_conv^T hi bf16
    unsigned short* WlT = (unsigned short*)carve(128 * 128 * 2);  // W_conv^T lo bf16
    int* cntA           = (int*)carve((size_t)N * 4);
    int* cntB           = (int*)carve((size_t)N * 4);
    unsigned short* bsrcu = (unsigned short*)carve((size_t)N * 64 * 2);  // padded CSR (ushort)

    prep0<<<64, 256, 0, stream>>>(Wc, Wfc, WhT, WlT, WT, cntA, cntB, N);

    int g1 = (N + 127) / 128;  // gemm1 blocks (128 rows each, 4 waves x 32 rows)
    fat<<<NSCAT + g1, 256, 0, stream>>>(x, WhT, WlT, (unsigned short*)hb, esrc, edst,
                                        cntA, cntB, bsrcu, N, E);

    aggregate<<<((size_t)N * 64 + 255) / 256, 256, 0, stream>>>(
        hb, x, cntA, cntB, bsrcu, bc, gamma, beta, zb, N);

    gemm2<<<(N / 64 + 4) / 4, 256, 0, stream>>>((const unsigned short*)zb, WT, bfc, out, N);
}

// Round 3
// 196.506 us; speedup vs baseline: 1.0506x; 1.0506x over previous
//
#include <hip/hip_runtime.h>

#define C_DIM 128
#define EPS 1e-5f
#define CSTRIDE 16  // ints per counter slot = 64B: ONE counter per cache line (anti-false-sharing)

typedef __attribute__((ext_vector_type(8))) short short8;
typedef __attribute__((ext_vector_type(4))) float f32x4;

__device__ __forceinline__ unsigned bf16rn(float f) {
    unsigned u = __float_as_uint(f);
    return (u + 0x7fffu + ((u >> 16) & 1u)) >> 16;
}
__device__ __forceinline__ unsigned pack_bf16(float lo, float hi) {
    return bf16rn(lo) | (bf16rn(hi) << 16);
}
__device__ __forceinline__ float blo(unsigned u) { return __uint_as_float(u << 16); }
__device__ __forceinline__ float bhi(unsigned u) { return __uint_as_float(u & 0xffff0000u); }

// ---------------- prep0: zero padded counters (float4) + W transposes ----------------
__global__ void prep0(const float* __restrict__ W, const float* __restrict__ Wfc,
                      unsigned short* __restrict__ WhT, unsigned short* __restrict__ WlT,
                      unsigned short* __restrict__ WT,
                      float4* __restrict__ cz, int czn) {
    int gid = blockIdx.x * blockDim.x + threadIdx.x;
    int stride = gridDim.x * blockDim.x;
    for (int t = gid; t < 128 * 128; t += stride) {
        int c = t >> 7, k = t & 127;
        float v = W[k * 128 + c];
        unsigned hi = bf16rn(v);
        float fh = __uint_as_float(hi << 16);
        WhT[c * 128 + k] = (unsigned short)hi;
        WlT[c * 128 + k] = (unsigned short)bf16rn(v - fh);
    }
    for (int t = gid; t < 48 * 128; t += stride) {
        int nc = t >> 7, k = t & 127;
        WT[nc * 128 + k] = (unsigned short)((nc < 40) ? bf16rn(Wfc[k * 40 + nc]) : 0u);
    }
    float4 z = make_float4(0.f, 0.f, 0.f, 0.f);
    for (int t = gid; t < czn; t += stride) cz[t] = z;
}

// ---------------- FAT: gemm1 split-bf16 MFMA | edge scatter (padded counters) -------
// Counters are padded to 64B each: atomic RMWs to one line drop from ~100-200
// (16 packed counters x ~13 edges) to ~6.4 -> no per-line serialization wall.
// Each scatter thread handles 4 independent edges (4 atomics in flight).
__global__ __launch_bounds__(256, 4) void fat(const float* __restrict__ x,
                                              const unsigned short* __restrict__ WhT,
                                              const unsigned short* __restrict__ WlT,
                                              unsigned short* __restrict__ hbs,
                                              const int* __restrict__ esrc,
                                              const int* __restrict__ edst,
                                              int* __restrict__ cntA,
                                              int* __restrict__ cntB,
                                              unsigned short* __restrict__ bsrcu,
                                              int n, int e, int g1) {
    int b = blockIdx.x;
    int t = threadIdx.x;

    if (b < g1) {
        // ---- gemm1: h = x @ W_conv via 16x16x32 bf16 MFMA, hi/lo split, no LDS ----
        int r0 = b * 128;
        int wid = t >> 6, lane = t & 63;
        int mrow = lane & 15, quad = lane >> 4;
        int rb = r0 + wid * 32;  // wave owns 32 rows x 128 cols

        f32x4 acc[2][8];
#pragma unroll
        for (int m = 0; m < 2; m++)
#pragma unroll
            for (int nn = 0; nn < 8; nn++) acc[m][nn] = (f32x4){0.f, 0.f, 0.f, 0.f};

#pragma unroll
        for (int ks = 0; ks < 4; ks++) {
            short8 Ah[2], Al[2];
#pragma unroll
            for (int m = 0; m < 2; m++) {
                int r = rb + m * 16 + mrow;
                if (r >= n) r = n - 1;  // clamp loads; stores guarded
                const float* xp = &x[(long)r * C_DIM + ks * 32 + quad * 8];
                float4 va = *(const float4*)xp;
                float4 vb = *(const float4*)(xp + 4);
                float xv[8] = {va.x, va.y, va.z, va.w, vb.x, vb.y, vb.z, vb.w};
#pragma unroll
                for (int e8 = 0; e8 < 8; e8++) {
                    unsigned hi = bf16rn(xv[e8]);
                    Ah[m][e8] = (short)hi;
                    Al[m][e8] = (short)bf16rn(xv[e8] - __uint_as_float(hi << 16));
                }
            }
#pragma unroll
            for (int nn = 0; nn < 8; nn++) {
                int wof = (nn * 16 + mrow) * 128 + ks * 32 + quad * 8;
                short8 Bh = *(const short8*)&WhT[wof];
                short8 Bl = *(const short8*)&WlT[wof];
#pragma unroll
                for (int m = 0; m < 2; m++) {
                    acc[m][nn] = __builtin_amdgcn_mfma_f32_16x16x32_bf16(Ah[m], Bh, acc[m][nn], 0, 0, 0);
                    acc[m][nn] = __builtin_amdgcn_mfma_f32_16x16x32_bf16(Al[m], Bh, acc[m][nn], 0, 0, 0);
                    acc[m][nn] = __builtin_amdgcn_mfma_f32_16x16x32_bf16(Ah[m], Bl, acc[m][nn], 0, 0, 0);
                }
            }
        }
        // C/D layout (same as verified gemm2): row = quad*4 + reg, col = nn*16 + mrow
#pragma unroll
        for (int m = 0; m < 2; m++)
#pragma unroll
            for (int nn = 0; nn < 8; nn++) {
                int c = nn * 16 + mrow;
#pragma unroll
                for (int reg = 0; reg < 4; reg++) {
                    int r = rb + m * 16 + quad * 4 + reg;
                    if (r < n) hbs[(long)r * 128 + c] = (unsigned short)bf16rn(acc[m][nn][reg]);
                }
            }
    } else {
        // ---- scatter: 4 edges/thread; quarters 0-1 -> cntA/front, 2-3 -> cntB/back
        int sb = b - g1;
        int q = (e + 3) >> 2;
        int i0 = sb * 256 + t;
        int i1 = i0 + q, i2 = i0 + 2 * q, i3 = i0 + 3 * q;
        bool v0 = i0 < e, v1 = i1 < e, v2 = i2 < e, v3 = i3 < e;
        int d0 = v0 ? edst[i0] : 0, s0 = v0 ? esrc[i0] : 0;
        int d1 = v1 ? edst[i1] : 0, s1 = v1 ? esrc[i1] : 0;
        int d2 = v2 ? edst[i2] : 0, s2 = v2 ? esrc[i2] : 0;
        int d3 = v3 ? edst[i3] : 0, s3 = v3 ? esrc[i3] : 0;
        int p0 = v0 ? atomicAdd(&cntA[(long)d0 * CSTRIDE], 1) : 64;
        int p1 = v1 ? atomicAdd(&cntA[(long)d1 * CSTRIDE], 1) : 64;
        int p2 = v2 ? atomicAdd(&cntB[(long)d2 * CSTRIDE], 1) : 64;
        int p3 = v3 ? atomicAdd(&cntB[(long)d3 * CSTRIDE], 1) : 64;
        if (p0 < 64) bsrcu[(long)d0 * 64 + p0] = (unsigned short)s0;
        if (p1 < 64) bsrcu[(long)d1 * 64 + p1] = (unsigned short)s1;
        if (p2 < 64) bsrcu[(long)d2 * 64 + 63 - p2] = (unsigned short)s2;
        if (p3 < 64) bsrcu[(long)d3 * 64 + 63 - p3] = (unsigned short)s3;
    }
}

// ---------------- fused aggregate + bias + relu*x + LN + residual --------------
// One wave per node; slot table (src id + weight) built once across the 64 lanes.
// Gather loop is WAVE-UNIFORM (round-1 lesson: __shfl from an inactive lane
// returns 0 -> divergent trip counts silently drop neighbors). 4 uint4 gathers
// in flight per iteration (16 slots) — most nodes (deg<=16) finish in ONE iter.
__global__ __launch_bounds__(256) void aggregate(const unsigned* __restrict__ hb,
                                                 const float* __restrict__ x,
                                                 const int* __restrict__ cntA,
                                                 const int* __restrict__ cntB,
                                                 const unsigned short* __restrict__ bsrcu,
                                                 const float* __restrict__ bconv,
                                                 const float* __restrict__ gamma,
                                                 const float* __restrict__ beta,
                                                 unsigned* __restrict__ zb, int n) {
    int wid = (blockIdx.x * blockDim.x + threadIdx.x) >> 6;
    if (wid >= n) return;  // wave-uniform
    int lane = threadIdx.x & 63;
    int sub = lane & 15, grp = lane >> 4;
    int i = wid;

    // hoist independent loads (overlap with slot-table construction)
    uint4 us = *(const uint4*)(hb + (long)i * 64 + sub * 4);
    float4 xa = *(const float4*)&x[(long)i * C_DIM + sub * 8];
    float4 xb = *(const float4*)&x[(long)i * C_DIM + sub * 8 + 4];

    int dA = cntA[(long)i * CSTRIDE], dB = cntB[(long)i * CSTRIDE];
    float di = rsqrtf((float)(dA + dB) + 1.0f);  // full degree for norm
    if (dA > 64) dA = 64;
    if (dB > 64 - dA) dB = 64 - dA;
    int tot = dA + dB;
    int shift = 64 - tot;  // maps compact index t in [dA,tot) to back region

    // slot table: lane <-> bucket slot (front region [0,dA), back [64-dB,64))
    int sraw = (int)bsrcu[(long)i * 64 + lane];
    bool valid = (lane < dA) | (lane >= 64 - dB);
    int s_all = valid ? sraw : 0;
    float w_all = 0.f;
    if (valid)
        w_all = rsqrtf((float)(cntA[(long)s_all * CSTRIDE] + cntB[(long)s_all * CSTRIDE]) + 1.0f) * di;

    float wself = (grp == 0) ? di * di : 0.f;
    float acc[8];
    acc[0] = wself * blo(us.x); acc[1] = wself * bhi(us.x);
    acc[2] = wself * blo(us.y); acc[3] = wself * bhi(us.y);
    acc[4] = wself * blo(us.z); acc[5] = wself * bhi(us.z);
    acc[6] = wself * blo(us.w); acc[7] = wself * bhi(us.w);

    int nIt = (tot + 15) >> 4;  // UNIFORM trip count; 16 slots (4 per grp) per iter
    for (int it = 0; it < nIt; ++it) {
        int tb = grp + it * 16;
        int ss[4];
        float ww[4];
#pragma unroll
        for (int qq = 0; qq < 4; qq++) {
            int tq = tb + qq * 4;
            int slq = ((tq < dA) ? tq : tq + shift) & 63;
            int sq = __shfl(s_all, slq);  // full-exec bpermute
            float wq = __shfl(w_all, slq);
            if (tq >= tot) { wq = 0.f; sq = i; }  // predicate AFTER shuffle (self row = L1 hit)
            ss[qq] = sq;
            ww[qq] = wq;
        }
        uint4 u[4];
#pragma unroll
        for (int qq = 0; qq < 4; qq++) u[qq] = *(const uint4*)(hb + (long)ss[qq] * 64 + sub * 4);
#pragma unroll
        for (int qq = 0; qq < 4; qq++) {
            float w = ww[qq];
            acc[0] += w * blo(u[qq].x); acc[1] += w * bhi(u[qq].x);
            acc[2] += w * blo(u[qq].y); acc[3] += w * bhi(u[qq].y);
            acc[4] += w * blo(u[qq].z); acc[5] += w * bhi(u[qq].z);
            acc[6] += w * blo(u[qq].w); acc[7] += w * bhi(u[qq].w);
        }
    }

#pragma unroll
    for (int j = 0; j < 8; j++) {
        acc[j] += __shfl_xor(acc[j], 16);
        acc[j] += __shfl_xor(acc[j], 32);
    }

    float4 bca = *(const float4*)&bconv[sub * 8];
    float4 bcb = *(const float4*)&bconv[sub * 8 + 4];
    float a[8], xv[8];
    xv[0] = xa.x; xv[1] = xa.y; xv[2] = xa.z; xv[3] = xa.w;
    xv[4] = xb.x; xv[5] = xb.y; xv[6] = xb.z; xv[7] = xb.w;
    float bc[8] = {bca.x, bca.y, bca.z, bca.w, bcb.x, bcb.y, bcb.z, bcb.w};
#pragma unroll
    for (int j = 0; j < 8; j++) a[j] = fmaxf(acc[j] + bc[j], 0.f) * xv[j];

    float s = a[0] + a[1] + a[2] + a[3] + a[4] + a[5] + a[6] + a[7];
#pragma unroll
    for (int off = 1; off < 16; off <<= 1) s += __shfl_xor(s, off);
    float mu = s * (1.0f / 128.0f);
    float d[8], v = 0.f;
#pragma unroll
    for (int j = 0; j < 8; j++) { d[j] = a[j] - mu; v += d[j] * d[j]; }
#pragma unroll
    for (int off = 1; off < 16; off <<= 1) v += __shfl_xor(v, off);
    float inv = rsqrtf(v * (1.0f / 128.0f) + EPS);

    if (grp == 0) {
        float4 ga = *(const float4*)&gamma[sub * 8];
        float4 gb = *(const float4*)&gamma[sub * 8 + 4];
        float4 ba = *(const float4*)&beta[sub * 8];
        float4 bb = *(const float4*)&beta[sub * 8 + 4];
        float g[8] = {ga.x, ga.y, ga.z, ga.w, gb.x, gb.y, gb.z, gb.w};
        float be[8] = {ba.x, ba.y, ba.z, ba.w, bb.x, bb.y, bb.z, bb.w};
        float o[8];
#pragma unroll
        for (int j = 0; j < 8; j++) o[j] = d[j] * inv * g[j] + be[j] + xv[j];
        uint4 p;
        p.x = pack_bf16(o[0], o[1]);
        p.y = pack_bf16(o[2], o[3]);
        p.z = pack_bf16(o[4], o[5]);
        p.w = pack_bf16(o[6], o[7]);
        *(uint4*)(zb + (long)i * 64 + sub * 4) = p;
    }
}

// ---------------- GEMM2: out = z @ W_fc + b_fc via bf16 MFMA, no LDS ----------------
__global__ __launch_bounds__(256) void gemm2(const unsigned short* __restrict__ zb,
                                             const unsigned short* __restrict__ WT,
                                             const float* __restrict__ bfc,
                                             float* __restrict__ out, int n) {
    int t = threadIdx.x;
    int w = t >> 6, lane = t & 63;
    int r0 = (blockIdx.x * 4 + w) * 64;
    if (r0 >= n) return;
    int mrow = lane & 15;
    int quad = lane >> 4;
    f32x4 acc[4][3];
#pragma unroll
    for (int m = 0; m < 4; m++)
#pragma unroll
        for (int nt = 0; nt < 3; nt++) acc[m][nt] = (f32x4){0.f, 0.f, 0.f, 0.f};
#pragma unroll
    for (int ks = 0; ks < 4; ks++) {
        short8 A[4], B[3];
#pragma unroll
        for (int m = 0; m < 4; m++) {
            int r = r0 + m * 16 + mrow;
            if (r >= n) r = n - 1;  // clamp (stores are guarded)
            A[m] = *(const short8*)&zb[(long)r * 128 + ks * 32 + quad * 8];
        }
#pragma unroll
        for (int nt = 0; nt < 3; nt++)
            B[nt] = *(const short8*)&WT[(nt * 16 + mrow) * 128 + ks * 32 + quad * 8];
#pragma unroll
        for (int m = 0; m < 4; m++)
#pragma unroll
            for (int nt = 0; nt < 3; nt++)
                acc[m][nt] = __builtin_amdgcn_mfma_f32_16x16x32_bf16(A[m], B[nt], acc[m][nt], 0, 0, 0);
    }
#pragma unroll
    for (int nt = 0; nt < 3; nt++) {
        int c = nt * 16 + mrow;
        if (c < 40) {
            float bias = bfc[c];
#pragma unroll
            for (int m = 0; m < 4; m++) {
#pragma unroll
                for (int reg = 0; reg < 4; reg++) {
                    int r = r0 + m * 16 + quad * 4 + reg;
                    if (r < n) out[(long)r * 40 + c] = acc[m][nt][reg] + bias;
                }
            }
        }
    }
}

extern "C" void kernel_launch(void* const* d_in, const int* in_sizes, int n_in,
                              void* d_out, int out_size, void* d_ws, size_t ws_size,
                              hipStream_t stream) {
    const float* x     = (const float*)d_in[0];
    const int*   ei    = (const int*)d_in[1];
    const float* Wc    = (const float*)d_in[2];
    const float* bc    = (const float*)d_in[3];
    const float* gamma = (const float*)d_in[4];
    const float* beta  = (const float*)d_in[5];
    const float* Wfc   = (const float*)d_in[6];
    const float* bfc   = (const float*)d_in[7];
    float* out = (float*)d_out;

    int N = in_sizes[0] / C_DIM;
    int E = in_sizes[1] / 2;
    const int* esrc = ei;
    const int* edst = ei + E;

    char* p = (char*)d_ws;
    auto carve = [&](size_t bytes) {
        void* q = (void*)p;
        p += (bytes + 255) & ~(size_t)255;
        return q;
    };
    unsigned* hb        = (unsigned*)carve((size_t)N * 64 * 4);   // h bf16 pairs
    unsigned* zb        = (unsigned*)carve((size_t)N * 64 * 4);   // z bf16 pairs
    unsigned short* WT  = (unsigned short*)carve(48 * 128 * 2);   // W_fc^T bf16
    unsigned short* WhT = (unsigned short*)carve(128 * 128 * 2);  // W_conv^T hi bf16
    unsigned short* WlT = (unsigned short*)carve(128 * 128 * 2);  // W_conv^T lo bf16
    int* cntA           = (int*)carve((size_t)N * CSTRIDE * 4);   // padded: 1 counter / 64B line
    int* cntB           = (int*)carve((size_t)N * CSTRIDE * 4);
    unsigned short* bsrcu = (unsigned short*)carve((size_t)N * 64 * 2);  // padded CSR (ushort)

    // cntA & cntB are contiguous (each N*CSTRIDE*4 = multiple of 256B): zero both at once
    int czn = (N * CSTRIDE * 2) / 4;  // float4 count
    prep0<<<256, 256, 0, stream>>>(Wc, Wfc, WhT, WlT, WT, (float4*)cntA, czn);

    int g1 = (N + 127) / 128;         // gemm1 blocks (128 rows each)
    int nscat = (((E + 3) >> 2) + 255) / 256;  // 4 edges/thread
    fat<<<g1 + nscat, 256, 0, stream>>>(x, WhT, WlT, (unsigned short*)hb, esrc, edst,
                                        cntA, cntB, bsrcu, N, E, g1);

    aggregate<<<((size_t)N * 64 + 255) / 256, 256, 0, stream>>>(
        hb, x, cntA, cntB, bsrcu, bc, gamma, beta, zb, N);

    gemm2<<<(N / 64 + 4) / 4, 256, 0, stream>>>((const unsigned short*)zb, WT, bfc, out, N);
}